// Round 6
// baseline (1753.710 us; speedup 1.0000x reference)
//
#include <hip/hip_runtime.h>
#include <math.h>

// Problem constants
#define B_   512
#define R_   5
#define NN   64
#define F_   172
#define T_   100
#define EF_  172
#define E_   272   // F+T
#define KD   444   // F+EF+T
#define DH   136   // E/H
#define OUT_ 172
#define CAT_ (R_*E_ + F_)  // 1532

// Fully fused, all-fp32, einsum-reordered:
//   scores: s_h[n] = (Wk_h^T q_h) . kin[n]        (never materialize K)
//   attn:   attn   = Wv . (sum_n w_h[n] kin[n])   (never materialize V)
// bk dropped: it shifts all scores of a (b,r,head) uniformly -> softmax-invariant.
__global__ __launch_bounds__(256) void fused_kernel(
    const float* __restrict__ src_node,   // [B,F]
    const float* __restrict__ src_time,   // [B,1,T]
    const float* __restrict__ nf,         // [B,R,N,F]
    const float* __restrict__ ntf,        // [B,R,N,T]
    const float* __restrict__ ef,         // [B,R,N,EF]
    const int*  __restrict__ mask,        // [R,B,N], nonzero = padded
    const float* __restrict__ Wq, const float* __restrict__ Wk, const float* __restrict__ Wv,
    const float* __restrict__ bq, const float* __restrict__ bv,
    const float* __restrict__ Wo, const float* __restrict__ bo,
    const float* __restrict__ W1, const float* __restrict__ b1,
    const float* __restrict__ W2, const float* __restrict__ b2,
    float* __restrict__ merged_out,       // [B,OUT]
    float* __restrict__ wavg_out)         // [B,R,N]
{
  __shared__ float xv[E_];
  __shared__ float qv[E_];
  __shared__ float qk[2][KD];      // per-head folded query-key vector
  __shared__ float sred[4][NN][2]; // per-wave score partials
  __shared__ float wsm[2][NN];     // softmax weights per head
  __shared__ float pvs[2][KD];     // per-head weighted kin sum
  __shared__ float attnv[E_];
  __shared__ float catv[CAT_];     // [stacked(R*E) | src_node(F)]
  __shared__ float h1[F_];
  __shared__ int   inv_s;

  const int tid  = threadIdx.x;
  const int b    = blockIdx.x;
  const int wave = tid >> 6;
  const int lane = tid & 63;

  for (int i = tid; i < E_; i += 256) {
    float v = (i < F_) ? src_node[(size_t)b * F_ + i]
                       : src_time[(size_t)b * T_ + (i - F_)];
    xv[i] = v;
    if (i < F_) catv[R_ * E_ + i] = v;
  }
  __syncthreads();

  for (int r = 0; r < R_; ++r) {
    // ---- q = Wq[r] @ x + bq[r] ----
    for (int f = tid; f < E_; f += 256) {
      const float* wr = Wq + ((size_t)(r * E_ + f)) * E_;
      float acc = bq[r * E_ + f];
      #pragma unroll 4
      for (int j = 0; j < E_; ++j) acc += wr[j] * xv[j];
      qv[f] = acc;
    }
    __syncthreads();

    // ---- qk_h[kd] = sum_{o in head h} qv[o] * Wk[r][o][kd]  (coalesced over kd) ----
    {
      const float* Wkr = Wk + (size_t)r * E_ * KD;
      const int kd0 = tid, kd1 = tid + 256;     // kd1 valid iff < 444
      float a00 = 0.f, a01 = 0.f, a10 = 0.f, a11 = 0.f;
      for (int o = 0; o < E_; ++o) {
        const float qo = qv[o];
        const float* row = Wkr + (size_t)o * KD;
        const float w0v = row[kd0];
        const float w1v = (kd1 < KD) ? row[kd1] : 0.f;
        if (o < DH) { a00 += qo * w0v; a01 += qo * w1v; }
        else        { a10 += qo * w0v; a11 += qo * w1v; }
      }
      qk[0][kd0] = a00; qk[1][kd0] = a10;
      if (kd1 < KD) { qk[0][kd1] = a01; qk[1][kd1] = a11; }
    }
    __syncthreads();

    // ---- scores: lane = neighbor, wave covers kd chunk of 111 ----
    {
      const size_t kinbase = ((size_t)(b * R_ + r)) * NN;
      const float* nfr  = nf  + (kinbase + lane) * F_;
      const float* efr  = ef  + (kinbase + lane) * EF_;
      const float* ntfr = ntf + (kinbase + lane) * T_;
      const int kdlo = wave * 111;
      float s0 = 0.f, s1 = 0.f;
      #pragma unroll 4
      for (int i = 0; i < 111; ++i) {
        const int kd = kdlo + i;
        const float kv = (kd < F_) ? nfr[kd]
                       : (kd < F_ + EF_) ? efr[kd - F_]
                       : ntfr[kd - F_ - EF_];
        s0 += qk[0][kd] * kv;
        s1 += qk[1][kd] * kv;
      }
      sred[wave][lane][0] = s0;
      sred[wave][lane][1] = s1;
    }
    __syncthreads();

    // ---- softmax over neighbors (wave 0; lane = n) ----
    if (tid < NN) {
      const int n = tid;
      float sc0 = sred[0][n][0] + sred[1][n][0] + sred[2][n][0] + sred[3][n][0];
      float sc1 = sred[0][n][1] + sred[1][n][1] + sred[2][n][1] + sred[3][n][1];
      const float scale = 0.085749292571254f;  // 1/sqrt(136)
      sc0 *= scale; sc1 *= scale;
      const int m = (mask[((size_t)r * B_ + b) * NN + n] != 0);
      const unsigned long long bal = __ballot(m);
      const int invalid = (bal == 0xFFFFFFFFFFFFFFFFull) ? 1 : 0;
      const int m2 = m && !(invalid && (n == 0));
      if (m2) { sc0 = -INFINITY; sc1 = -INFINITY; }
      float mx0 = sc0, mx1 = sc1;
      for (int off = 32; off; off >>= 1) {
        mx0 = fmaxf(mx0, __shfl_xor(mx0, off));
        mx1 = fmaxf(mx1, __shfl_xor(mx1, off));
      }
      const float e0 = m2 ? 0.f : __expf(sc0 - mx0);
      const float e1 = m2 ? 0.f : __expf(sc1 - mx1);
      float su0 = e0, su1 = e1;
      for (int off = 32; off; off >>= 1) {
        su0 += __shfl_xor(su0, off);
        su1 += __shfl_xor(su1, off);
      }
      const float w0 = e0 / su0, w1 = e1 / su1;
      wsm[0][n] = w0; wsm[1][n] = w1;
      if (n == 0) inv_s = invalid;
      wavg_out[((size_t)b * R_ + r) * NN + n] = invalid ? 0.f : 0.5f * (w0 + w1);
    }
    __syncthreads();

    // ---- pv_h[kd] = sum_n w_h[n] * kin[n][kd]  (coalesced over kd) ----
    {
      const size_t kinbase = ((size_t)(b * R_ + r)) * NN;
      const int kd0 = tid, kd1 = tid + 256;
      float p00 = 0.f, p01 = 0.f, p10 = 0.f, p11 = 0.f;
      for (int n = 0; n < NN; ++n) {
        const float w0 = wsm[0][n], w1 = wsm[1][n];
        const size_t row = kinbase + n;
        const float v0 = (kd0 < F_) ? nf[row * F_ + kd0]
                                    : ef[row * EF_ + (kd0 - F_)];   // kd0<344 always
        p00 += w0 * v0; p10 += w1 * v0;
        if (kd1 < KD) {
          const float v1 = (kd1 < F_ + EF_) ? ef[row * EF_ + (kd1 - F_)]
                                            : ntf[row * T_ + (kd1 - F_ - EF_)];
          p01 += w0 * v1; p11 += w1 * v1;
        }
      }
      pvs[0][kd0] = p00; pvs[1][kd0] = p10;
      if (kd1 < KD) { pvs[0][kd1] = p01; pvs[1][kd1] = p11; }
    }
    __syncthreads();

    // ---- attn[o] = Wv[r][o] . pv_{h(o)} + bv[r][o] ----
    for (int o = tid; o < E_; o += 256) {
      const float* wr = Wv + ((size_t)(r * E_ + o)) * KD;
      const float* ph = pvs[(o < DH) ? 0 : 1];
      float acc = bv[r * E_ + o];
      #pragma unroll 4
      for (int j = 0; j < KD; ++j) acc += wr[j] * ph[j];
      attnv[o] = acc;
    }
    __syncthreads();

    // ---- catv[r*E + f] = Wo[r] @ attn + bo[r]  (0 if invalid) ----
    {
      const int invalid = inv_s;
      for (int f = tid; f < E_; f += 256) {
        const float* wr = Wo + ((size_t)(r * E_ + f)) * E_;
        float acc = bo[r * E_ + f];
        #pragma unroll 4
        for (int j = 0; j < E_; ++j) acc += wr[j] * attnv[j];
        catv[r * E_ + f] = invalid ? 0.f : acc;
      }
    }
    __syncthreads();
  }

  // ---- MergeLayer: out = W2 @ relu(W1 @ catv + b1) + b2 ----
  if (tid < F_) {
    const float* wr = W1 + (size_t)tid * CAT_;
    float acc = b1[tid];
    #pragma unroll 4
    for (int j = 0; j < CAT_; ++j) acc += wr[j] * catv[j];
    h1[tid] = fmaxf(acc, 0.f);
  }
  __syncthreads();

  if (tid < OUT_) {
    const float* wr = W2 + (size_t)tid * F_;
    float acc = b2[tid];
    #pragma unroll 4
    for (int j = 0; j < F_; ++j) acc += wr[j] * h1[j];
    merged_out[(size_t)b * OUT_ + tid] = acc;
  }
}

extern "C" void kernel_launch(void* const* d_in, const int* in_sizes, int n_in,
                              void* d_out, int out_size, void* d_ws, size_t ws_size,
                              hipStream_t stream) {
  const float* src_node = (const float*)d_in[0];
  const float* src_time = (const float*)d_in[1];
  const float* nf       = (const float*)d_in[2];
  const float* ntf      = (const float*)d_in[3];
  const float* ef       = (const float*)d_in[4];
  const int*   mask     = (const int*)d_in[5];
  const float* Wq = (const float*)d_in[6];
  const float* Wk = (const float*)d_in[7];
  const float* Wv = (const float*)d_in[8];
  const float* bq = (const float*)d_in[9];
  // d_in[10] = bk (unused: uniform score shift, softmax-invariant)
  const float* bv = (const float*)d_in[11];
  const float* Wo = (const float*)d_in[12];
  const float* bo = (const float*)d_in[13];
  const float* W1 = (const float*)d_in[14];
  const float* b1 = (const float*)d_in[15];
  const float* W2 = (const float*)d_in[16];
  const float* b2 = (const float*)d_in[17];

  float* out_merged = (float*)d_out;                      // [B, OUT]
  float* out_wavg   = out_merged + (size_t)B_ * OUT_;     // [B, R, N]

  fused_kernel<<<B_, 256, 0, stream>>>(
      src_node, src_time, nf, ntf, ef, mask,
      Wq, Wk, Wv, bq, bv, Wo, bo,
      W1, b1, W2, b2,
      out_merged, out_wavg);
}